// Round 7
// baseline (280.197 us; speedup 1.0000x reference)
//
#include <hip/hip_runtime.h>
#include <math.h>

// NoisyTopkRouter: B=8,S=4096,D=1024,E=64,k=2
// R7: LDS-free K-loop. fp16x3-emulated MFMA (32x32x16), verified R3-R6:
//   C = A_hi*B_hi + (A_hi*B_lo' + A_lo'*B_hi)/2048
// split_B pre-pass (R6-verified): B in fp16 hi/lo MFMA-fragment order in ws.
// Main: block = 32 tokens, 4 waves; wave w owns expert group w (32 experts),
// full K=1024. A loaded DIRECTLY from global in fragment layout (lane pair
// covers 64B of a row; consecutive tiles consume full 128B lines via L1;
// 4 waves reuse lines). No LDS, no barriers, no lgkm round-trip in K-loop.
// Grid 1024 blocks x 4 waves = 4/SIMD, whole grid co-resident.
// Epilogue: Cs transpose overlay + R1-R6-verified softplus/softmax/top2.

#define DIM 1024
#define NEXP 64
#define CS 132              // Cs row stride in floats
#define LOSCALE 2048.0f
#define INV_LOSCALE (1.0f / 2048.0f)

using half4v   = __attribute__((ext_vector_type(4)))  _Float16;
using half8v   = __attribute__((ext_vector_type(8)))  _Float16;
using floatx16 = __attribute__((ext_vector_type(16))) float;

__device__ inline void split4(const float4 v, half4v& hi, half4v& lo) {
    _Float16 h0 = (_Float16)v.x, h1 = (_Float16)v.y,
             h2 = (_Float16)v.z, h3 = (_Float16)v.w;
    hi = (half4v){h0, h1, h2, h3};
    lo = (half4v){(_Float16)((v.x - (float)h0) * LOSCALE),
                  (_Float16)((v.y - (float)h1) * LOSCALE),
                  (_Float16)((v.z - (float)h2) * LOSCALE),
                  (_Float16)((v.w - (float)h3) * LOSCALE)};
}

__device__ inline half8v mk8(const half4v a, const half4v b) {
    return (half8v){a[0], a[1], a[2], a[3], b[0], b[1], b[2], b[3]};
}

#define MFMA32(a, b, c) __builtin_amdgcn_mfma_f32_32x32x16_f16((a), (b), (c), 0, 0, 0)

// ---- pre-pass: split W (Wl++Wn) into fp16 hi/lo in MFMA-fragment order ----
// g = ((nc*64 + t)*64 + lane); element = W[e=nc*32+(lane&31)][k=t*16+(lane>>5)*8+j]
__global__ __launch_bounds__(64)
void split_B(const float* __restrict__ Wl, const float* __restrict__ Wn,
             _Float16* __restrict__ bhi, _Float16* __restrict__ blo)
{
    const int g = blockIdx.x * 64 + threadIdx.x;    // 0..16383
    const int lane = g & 63;
    const int t    = (g >> 6) & 63;
    const int nc   = g >> 12;
    const int e = nc * 32 + (lane & 31);
    const int k = t * 16 + (lane >> 5) * 8;
    const float* W = ((e < NEXP) ? (Wl + (size_t)e * DIM)
                                 : (Wn + (size_t)(e - NEXP) * DIM)) + k;
    float4 v0 = *(const float4*)(W);
    float4 v1 = *(const float4*)(W + 4);
    half4v h0, l0, h1, l1;
    split4(v0, h0, l0);
    split4(v1, h1, l1);
    *(half8v*)(bhi + (size_t)g * 8) = mk8(h0, h1);
    *(half8v*)(blo + (size_t)g * 8) = mk8(l0, l1);
}

// ---- main kernel ----
__global__ __launch_bounds__(256, 4)
void router_main(const float* __restrict__ h, const _Float16* __restrict__ bhi,
                 const _Float16* __restrict__ blo, const float* __restrict__ bl,
                 const float* __restrict__ bn, const float* __restrict__ noise,
                 float* __restrict__ outR, float* __restrict__ outIx,
                 float* __restrict__ outF, int M)
{
    __shared__ float Cs[32 * CS];       // 16896 B

    const int tid   = threadIdx.x;      // 0..255
    const int wv    = tid >> 6;         // expert group nc = wv
    const int lane  = tid & 63;
    const int row31 = lane & 31;
    const int oct   = lane >> 5;
    const int tok0  = blockIdx.x * 32;

    // A fragment pointer: lane covers h[tok0+row31][t*16 + oct*8 .. +8)
    const float* hp = h + (size_t)(tok0 + row31) * DIM + oct * 8;
    // B fragment pointers (tile stride 512 halves)
    const _Float16* bbh = bhi + (size_t)(wv * 64) * 512 + lane * 8;
    const _Float16* bbl = blo + (size_t)(wv * 64) * 512 + lane * 8;

    floatx16 acc1, acc2;
#pragma unroll
    for (int i = 0; i < 16; i++) { acc1[i] = 0.f; acc2[i] = 0.f; }

    // depth-1 software pipeline, no LDS, no barriers
    float4 a0c = *(const float4*)(hp);
    float4 a1c = *(const float4*)(hp + 4);
    half8v bhc = *(const half8v*)(bbh);
    half8v blc = *(const half8v*)(bbl);

#pragma unroll 4
    for (int t = 0; t < 64; t++) {
        float4 a0n, a1n; half8v bhn, bln;
        if (t + 1 < 64) {
            a0n = *(const float4*)(hp + (t + 1) * 16);
            a1n = *(const float4*)(hp + (t + 1) * 16 + 4);
            bhn = *(const half8v*)(bbh + (t + 1) * 512);
            bln = *(const half8v*)(bbl + (t + 1) * 512);
        }
        half4v h0, l0, h1, l1;
        split4(a0c, h0, l0);
        split4(a1c, h1, l1);
        half8v aH = mk8(h0, h1), aL = mk8(l0, l1);
        acc1 = MFMA32(aH, bhc, acc1);
        acc2 = MFMA32(aH, blc, acc2);
        acc2 = MFMA32(aL, bhc, acc2);
        a0c = a0n; a1c = a1n; bhc = bhn; blc = bln;
    }

    // ---- Cs transpose: col=lane&31, row=(i&3)+8*(i>>2)+4*oct (verified) ----
#pragma unroll
    for (int i = 0; i < 16; i++) {
        int rowt = (i & 3) + 8 * (i >> 2) + 4 * oct;
        Cs[rowt * CS + wv * 32 + row31] = acc1[i] + acc2[i] * INV_LOSCALE;
    }
    __syncthreads();

    // ---- epilogue: wave wv -> tokens wv*8..+7, lane = expert (verified) ----
    const float blv = bl[lane];
    const float bnv = bn[lane];

    for (int i = 0; i < 8; i++) {
        const int t = wv * 8 + i;
        const int gt = tok0 + t;
        float xr = Cs[t * CS + lane] + blv;
        float xf = Cs[t * CS + 64 + lane] + bnv;
        float nz = noise[(size_t)gt * NEXP + lane];

        // softplus (matches jax.nn.softplus)
        float stdv = fmaxf(xf, 0.f) + log1pf(expf(-fabsf(xf)));
        float noisy = fmaf(nz, stdv, xr);

        // full softmax over 64 lanes
        float m = noisy;
#pragma unroll
        for (int o = 32; o > 0; o >>= 1) m = fmaxf(m, __shfl_xor(m, o, 64));
        float p = expf(noisy - m);
        float s = p;
#pragma unroll
        for (int o = 32; o > 0; o >>= 1) s += __shfl_xor(s, o, 64);
        float fullp = p / s;

        // argmax #1 (ties -> lowest index, matching lax.top_k)
        float v = noisy; int idx = lane;
#pragma unroll
        for (int o = 32; o > 0; o >>= 1) {
            float ov = __shfl_xor(v, o, 64);
            int   oi = __shfl_xor(idx, o, 64);
            if (ov > v || (ov == v && oi < idx)) { v = ov; idx = oi; }
        }
        const float v1 = v; const int i1 = idx;
        // argmax #2
        v = (lane == i1) ? -INFINITY : noisy; idx = lane;
#pragma unroll
        for (int o = 32; o > 0; o >>= 1) {
            float ov = __shfl_xor(v, o, 64);
            int   oi = __shfl_xor(idx, o, 64);
            if (ov > v || (ov == v && oi < idx)) { v = ov; idx = oi; }
        }
        const float v2 = v; const int i2 = idx;

        // sparse softmax over {i1,i2}
        float e2 = expf(v2 - v1);
        float den = 1.f + e2;
        float routep = (lane == i1) ? (1.f / den) : ((lane == i2) ? (e2 / den) : 0.f);

        outR[(size_t)gt * NEXP + lane] = routep;
        outF[(size_t)gt * NEXP + lane] = fullp;
        if (lane == 0) {
            outIx[(size_t)gt * 2 + 0] = (float)i1;
            outIx[(size_t)gt * 2 + 1] = (float)i2;
        }
    }
}

extern "C" void kernel_launch(void* const* d_in, const int* in_sizes, int n_in,
                              void* d_out, int out_size, void* d_ws, size_t ws_size,
                              hipStream_t stream) {
    const float* h     = (const float*)d_in[0];
    const float* Wl    = (const float*)d_in[1];
    const float* bl    = (const float*)d_in[2];
    const float* Wn    = (const float*)d_in[3];
    const float* bn    = (const float*)d_in[4];
    const float* noise = (const float*)d_in[5];
    float* out = (float*)d_out;

    const int M = in_sizes[0] / DIM;                 // 32768
    float* outR  = out;                              // [M,64]
    float* outIx = out + (size_t)M * NEXP;           // [M,2]
    float* outF  = outIx + (size_t)M * 2;            // [M,64]

    _Float16* bhi = (_Float16*)d_ws;                 // 128*1024 halves = 256 KB
    _Float16* blo = bhi + 128 * DIM;                 // +256 KB

    split_B<<<256, 64, 0, stream>>>(Wl, Wn, bhi, blo);
    router_main<<<M / 32, 256, 0, stream>>>(h, bhi, blo, bl, bn, noise,
                                            outR, outIx, outF, M);
}